// Round 1
// baseline (701.889 us; speedup 1.0000x reference)
//
#include <hip/hip_runtime.h>

// GraphSAGE mean aggregator on MI355X.
// feat [N,128] f32, src/dst [E] i32, W_self/W_neigh [128,128] f32, biases [128].
// out = feat@W_self + b_self + b_neigh + (segment_sum(feat@W_neigh [src], dst)/max(deg,1))
// (per-row scale commutes with right-matmul, so we scatter transformed rows.)

constexpr int N_NODES = 100000;
constexpr int N_EDGES = 640000;
constexpr int D = 128;

__global__ void zero_deg_kernel(int* __restrict__ deg) {
    int i = blockIdx.x * blockDim.x + threadIdx.x;
    if (i < N_NODES) deg[i] = 0;
}

__global__ void deg_kernel(const int* __restrict__ dst, int* __restrict__ deg) {
    int e = blockIdx.x * blockDim.x + threadIdx.x;
    if (e < N_EDGES) atomicAdd(&deg[dst[e]], 1);
}

__global__ void invdeg_kernel(const int* __restrict__ deg, float* __restrict__ invdeg) {
    int i = blockIdx.x * blockDim.x + threadIdx.x;
    if (i < N_NODES) invdeg[i] = 1.0f / (float)max(deg[i], 1);
}

// out[row][c] = sum_k feat[row][k] * W[k][c]  (+ b0[c] + b1[c] if non-null)
// Block = 512 threads = 8 waves. Each wave handles 8 rows at a time; lane owns
// cols {lane, lane+64}. W staged in LDS (64KB); 8 feat rows per wave staged in
// LDS (4KB/wave). Register blocking: each LDS W element feeds 16 FMAs.
__global__ __launch_bounds__(512) void mm_kernel(
    const float* __restrict__ feat, const float* __restrict__ W,
    const float* __restrict__ b0, const float* __restrict__ b1,
    float* __restrict__ out)
{
    __shared__ float lw[D][D];        // 64 KB
    __shared__ float lf[8][8][D];     // 8 waves x 8 rows x 128 = 32 KB

    const int tid = threadIdx.x;
    // Stage W into LDS, coalesced float4.
    {
        const float4* Wv = (const float4*)W;
        float4* lwv = (float4*)&lw[0][0];
        for (int i = tid; i < D * D / 4; i += 512) lwv[i] = Wv[i];
    }
    __syncthreads();

    const int wave = tid >> 6;
    const int lane = tid & 63;

    float bias0 = 0.0f, bias1 = 0.0f;
    if (b0) { bias0 += b0[lane]; bias1 += b0[lane + 64]; }
    if (b1) { bias0 += b1[lane]; bias1 += b1[lane + 64]; }

    const int gw = blockIdx.x * 8 + wave;     // global wave id
    const int nwaves = gridDim.x * 8;

    for (int row0 = gw * 8; row0 < N_NODES; row0 += nwaves * 8) {
        // Stage 8 feat rows (1024 floats = 256 float4) cooperatively (wave-local).
        {
            const float4* fv = (const float4*)(feat + (size_t)row0 * D);
            float4* lfv = (float4*)&lf[wave][0][0];
            const int limit = min(8, N_NODES - row0) * (D / 4);
            #pragma unroll
            for (int i = 0; i < 4; i++) {
                int idx = lane + i * 64;
                lfv[idx] = (idx < limit) ? fv[idx] : float4{0.f, 0.f, 0.f, 0.f};
            }
        }
        // wave-local LDS producer/consumer: compiler inserts lgkmcnt wait, no barrier needed

        float acc[8][2];
        #pragma unroll
        for (int r = 0; r < 8; r++) { acc[r][0] = 0.f; acc[r][1] = 0.f; }

        for (int k = 0; k < D; k += 4) {
            float4 f4[8];
            #pragma unroll
            for (int r = 0; r < 8; r++)
                f4[r] = *(const float4*)&lf[wave][r][k];
            #pragma unroll
            for (int kk = 0; kk < 4; kk++) {
                const float w0 = lw[k + kk][lane];
                const float w1 = lw[k + kk][lane + 64];
                #pragma unroll
                for (int r = 0; r < 8; r++) {
                    const float f = ((const float*)&f4[r])[kk];
                    acc[r][0] = fmaf(f, w0, acc[r][0]);
                    acc[r][1] = fmaf(f, w1, acc[r][1]);
                }
            }
        }

        const int rmax = min(8, N_NODES - row0);
        for (int r = 0; r < rmax; r++) {
            out[(size_t)(row0 + r) * D + lane]      = acc[r][0] + bias0;
            out[(size_t)(row0 + r) * D + lane + 64] = acc[r][1] + bias1;
        }
    }
}

// For each edge: out[dst] += t[src] * invdeg[dst].  One wave per edge; lane
// covers 2 consecutive floats (float2 load, 2 f32 atomics).
__global__ void scatter_kernel(const float* __restrict__ t,
                               const int* __restrict__ src,
                               const int* __restrict__ dst,
                               const float* __restrict__ invdeg,
                               float* __restrict__ out)
{
    const int lane = threadIdx.x & 63;
    const int wid = (blockIdx.x * blockDim.x + threadIdx.x) >> 6;
    const int nw = (gridDim.x * blockDim.x) >> 6;

    for (int e = wid; e < N_EDGES; e += nw) {
        const int s = src[e];
        const int d = dst[e];
        const float sc = invdeg[d];
        const float2 v = ((const float2*)(t + (size_t)s * D))[lane];
        float* orow = out + (size_t)d * D + lane * 2;
        atomicAdd(&orow[0], v.x * sc);
        atomicAdd(&orow[1], v.y * sc);
    }
}

extern "C" void kernel_launch(void* const* d_in, const int* in_sizes, int n_in,
                              void* d_out, int out_size, void* d_ws, size_t ws_size,
                              hipStream_t stream) {
    const float* feat   = (const float*)d_in[0];
    const int*   src    = (const int*)d_in[1];
    const int*   dst    = (const int*)d_in[2];
    const float* W_self = (const float*)d_in[3];
    const float* b_self = (const float*)d_in[4];
    const float* W_neigh= (const float*)d_in[5];
    const float* b_neigh= (const float*)d_in[6];
    float* out = (float*)d_out;

    // ws layout: t [N*D f32] | deg [N i32] | invdeg [N f32]
    float* t      = (float*)d_ws;
    int*   deg    = (int*)(t + (size_t)N_NODES * D);
    float* invdeg = (float*)(deg + N_NODES);

    zero_deg_kernel<<<(N_NODES + 255) / 256, 256, 0, stream>>>(deg);
    deg_kernel<<<(N_EDGES + 255) / 256, 256, 0, stream>>>(dst, deg);
    invdeg_kernel<<<(N_NODES + 255) / 256, 256, 0, stream>>>(deg, invdeg);

    // t = feat @ W_neigh (no bias); out = feat @ W_self + b_self + b_neigh
    mm_kernel<<<256, 512, 0, stream>>>(feat, W_neigh, nullptr, nullptr, t);
    mm_kernel<<<256, 512, 0, stream>>>(feat, W_self, b_self, b_neigh, out);

    scatter_kernel<<<2048, 256, 0, stream>>>(t, src, dst, invdeg, out);
}

// Round 2
// 545.522 us; speedup vs baseline: 1.2866x; 1.2866x over previous
//
#include <hip/hip_runtime.h>

// GraphSAGE mean aggregator on MI355X.
// out = feat@W_self + b_self + b_neigh + segment_mean(t[src], dst),  t = feat@W_neigh
// (per-row 1/deg scale commutes with the right-matmul).
// R2: replaced 82M-float-atomic scatter with device-built CSR + gather-side
// reduction (one wave per node, register accumulate, single non-atomic write).

constexpr int N_NODES = 100000;
constexpr int N_EDGES = 640000;
constexpr int D = 128;

__global__ void zero_deg_kernel(int* __restrict__ deg) {
    int i = blockIdx.x * blockDim.x + threadIdx.x;
    if (i < N_NODES) deg[i] = 0;
}

__global__ void deg_kernel(const int* __restrict__ dst, int* __restrict__ deg) {
    int e = blockIdx.x * blockDim.x + threadIdx.x;
    if (e < N_EDGES) atomicAdd(&deg[dst[e]], 1);
}

__global__ void invdeg_kernel(const int* __restrict__ deg, float* __restrict__ invdeg) {
    int i = blockIdx.x * blockDim.x + threadIdx.x;
    if (i < N_NODES) invdeg[i] = 1.0f / (float)max(deg[i], 1);
}

// Single-block exclusive scan of deg[0..N) -> rowptr[0..N], rowptr[N]=E.
// Also initializes cursor[i] = rowptr[i] for the counting-sort fill.
__global__ __launch_bounds__(1024) void scan_kernel(const int* __restrict__ deg,
                                                    int* __restrict__ rowptr,
                                                    int* __restrict__ cursor) {
    __shared__ int ssum[1024];
    const int tid = threadIdx.x;
    const int chunk = (N_NODES + 1023) / 1024;   // 98
    const int base = tid * chunk;

    int s = 0;
    for (int i = 0; i < chunk; i++) {
        int idx = base + i;
        if (idx < N_NODES) s += deg[idx];
    }
    ssum[tid] = s;
    __syncthreads();
    // Hillis-Steele inclusive scan in LDS.
    for (int off = 1; off < 1024; off <<= 1) {
        int v = (tid >= off) ? ssum[tid - off] : 0;
        __syncthreads();
        ssum[tid] += v;
        __syncthreads();
    }
    int run = ssum[tid] - s;   // exclusive prefix for this chunk
    for (int i = 0; i < chunk; i++) {
        int idx = base + i;
        if (idx < N_NODES) {
            rowptr[idx] = run;
            cursor[idx] = run;
            run += deg[idx];
        }
    }
    if (tid == 1023) rowptr[N_NODES] = run;   // = N_EDGES
}

__global__ void fill_kernel(const int* __restrict__ src, const int* __restrict__ dst,
                            int* __restrict__ cursor, int* __restrict__ csr_src) {
    int e = blockIdx.x * blockDim.x + threadIdx.x;
    if (e < N_EDGES) {
        int pos = atomicAdd(&cursor[dst[e]], 1);
        csr_src[pos] = src[e];
    }
}

// out[row][c] = sum_k feat[row][k] * W[k][c]  (+ b0[c] + b1[c] if non-null)
// Block = 512 threads = 8 waves; W staged in LDS; 8 rows x 2 cols per lane.
__global__ __launch_bounds__(512) void mm_kernel(
    const float* __restrict__ feat, const float* __restrict__ W,
    const float* __restrict__ b0, const float* __restrict__ b1,
    float* __restrict__ out)
{
    __shared__ float lw[D][D];        // 64 KB
    __shared__ float lf[8][8][D];     // 32 KB

    const int tid = threadIdx.x;
    {
        const float4* Wv = (const float4*)W;
        float4* lwv = (float4*)&lw[0][0];
        for (int i = tid; i < D * D / 4; i += 512) lwv[i] = Wv[i];
    }
    __syncthreads();

    const int wave = tid >> 6;
    const int lane = tid & 63;

    float bias0 = 0.0f, bias1 = 0.0f;
    if (b0) { bias0 += b0[lane]; bias1 += b0[lane + 64]; }
    if (b1) { bias0 += b1[lane]; bias1 += b1[lane + 64]; }

    const int gw = blockIdx.x * 8 + wave;
    const int nwaves = gridDim.x * 8;

    for (int row0 = gw * 8; row0 < N_NODES; row0 += nwaves * 8) {
        {
            const float4* fv = (const float4*)(feat + (size_t)row0 * D);
            float4* lfv = (float4*)&lf[wave][0][0];
            const int limit = min(8, N_NODES - row0) * (D / 4);
            #pragma unroll
            for (int i = 0; i < 4; i++) {
                int idx = lane + i * 64;
                lfv[idx] = (idx < limit) ? fv[idx] : float4{0.f, 0.f, 0.f, 0.f};
            }
        }

        float acc[8][2];
        #pragma unroll
        for (int r = 0; r < 8; r++) { acc[r][0] = 0.f; acc[r][1] = 0.f; }

        for (int k = 0; k < D; k += 4) {
            float4 f4[8];
            #pragma unroll
            for (int r = 0; r < 8; r++)
                f4[r] = *(const float4*)&lf[wave][r][k];
            #pragma unroll
            for (int kk = 0; kk < 4; kk++) {
                const float w0 = lw[k + kk][lane];
                const float w1 = lw[k + kk][lane + 64];
                #pragma unroll
                for (int r = 0; r < 8; r++) {
                    const float f = ((const float*)&f4[r])[kk];
                    acc[r][0] = fmaf(f, w0, acc[r][0]);
                    acc[r][1] = fmaf(f, w1, acc[r][1]);
                }
            }
        }

        const int rmax = min(8, N_NODES - row0);
        for (int r = 0; r < rmax; r++) {
            out[(size_t)(row0 + r) * D + lane]      = acc[r][0] + bias0;
            out[(size_t)(row0 + r) * D + lane + 64] = acc[r][1] + bias1;
        }
    }
}

// One wave per node: sum t[src] rows over in-edges (CSR), then
// out[n] += sum * invdeg[n].  Coalesced float2 per lane; no atomics.
__global__ void gather_kernel(const float* __restrict__ t,
                              const int* __restrict__ csr_src,
                              const int* __restrict__ rowptr,
                              const float* __restrict__ invdeg,
                              float* __restrict__ out)
{
    const int lane = threadIdx.x & 63;
    const int wid = (blockIdx.x * blockDim.x + threadIdx.x) >> 6;
    const int nw = (gridDim.x * blockDim.x) >> 6;

    for (int n = wid; n < N_NODES; n += nw) {
        const int e0 = rowptr[n];
        const int e1 = rowptr[n + 1];
        float ax = 0.f, ay = 0.f;
        for (int e = e0; e < e1; e++) {
            const int s = csr_src[e];
            const float2 v = ((const float2*)(t + (size_t)s * D))[lane];
            ax += v.x; ay += v.y;
        }
        const float sc = invdeg[n];
        float2* orow = (float2*)(out + (size_t)n * D) + lane;
        float2 o = *orow;
        o.x += ax * sc;
        o.y += ay * sc;
        *orow = o;
    }
}

extern "C" void kernel_launch(void* const* d_in, const int* in_sizes, int n_in,
                              void* d_out, int out_size, void* d_ws, size_t ws_size,
                              hipStream_t stream) {
    const float* feat    = (const float*)d_in[0];
    const int*   src     = (const int*)d_in[1];
    const int*   dst     = (const int*)d_in[2];
    const float* W_self  = (const float*)d_in[3];
    const float* b_self  = (const float*)d_in[4];
    const float* W_neigh = (const float*)d_in[5];
    const float* b_neigh = (const float*)d_in[6];
    float* out = (float*)d_out;

    // ws layout: t [N*D f32] | deg [N] | invdeg [N] | rowptr [N+1] | cursor [N] | csr_src [E]
    float* t       = (float*)d_ws;
    int*   deg     = (int*)(t + (size_t)N_NODES * D);
    float* invdeg  = (float*)(deg + N_NODES);
    int*   rowptr  = (int*)(invdeg + N_NODES);
    int*   cursor  = rowptr + (N_NODES + 1);
    int*   csr_src = cursor + N_NODES;

    zero_deg_kernel<<<(N_NODES + 255) / 256, 256, 0, stream>>>(deg);
    deg_kernel<<<(N_EDGES + 255) / 256, 256, 0, stream>>>(dst, deg);
    invdeg_kernel<<<(N_NODES + 255) / 256, 256, 0, stream>>>(deg, invdeg);
    scan_kernel<<<1, 1024, 0, stream>>>(deg, rowptr, cursor);
    fill_kernel<<<(N_EDGES + 255) / 256, 256, 0, stream>>>(src, dst, cursor, csr_src);

    // t = feat @ W_neigh (no bias); out = feat @ W_self + b_self + b_neigh
    mm_kernel<<<256, 512, 0, stream>>>(feat, W_neigh, nullptr, nullptr, t);
    mm_kernel<<<256, 512, 0, stream>>>(feat, W_self, b_self, b_neigh, out);

    gather_kernel<<<25000, 256, 0, stream>>>(t, csr_src, rowptr, invdeg, out);
}

// Round 3
// 293.992 us; speedup vs baseline: 2.3874x; 1.8556x over previous
//
#include <hip/hip_runtime.h>

// GraphSAGE mean aggregator on MI355X.
// out = feat@W_self + b_self + b_neigh + segment_mean(t[src], dst),  t = feat@W_neigh
// (per-row 1/deg scale commutes with the right-matmul).
// R2: CSR + gather-side reduction (no float atomics).
// R3: single-block scan (263us, 1 CU!) -> 3-phase parallel scan (~10us).

constexpr int N_NODES = 100000;
constexpr int N_EDGES = 640000;
constexpr int D = 128;

constexpr int SCAN_ELEMS_PER_BLOCK = 1024;   // 256 threads x 4
constexpr int SCAN_NBLOCKS = (N_NODES + SCAN_ELEMS_PER_BLOCK - 1) / SCAN_ELEMS_PER_BLOCK; // 98

__global__ void zero_deg_kernel(int* __restrict__ deg) {
    int i = blockIdx.x * blockDim.x + threadIdx.x;
    if (i < N_NODES) deg[i] = 0;
}

__global__ void deg_kernel(const int* __restrict__ dst, int* __restrict__ deg) {
    int e = blockIdx.x * blockDim.x + threadIdx.x;
    if (e < N_EDGES) atomicAdd(&deg[dst[e]], 1);
}

__global__ void invdeg_kernel(const int* __restrict__ deg, float* __restrict__ invdeg) {
    int i = blockIdx.x * blockDim.x + threadIdx.x;
    if (i < N_NODES) invdeg[i] = 1.0f / (float)max(deg[i], 1);
}

// ---- 3-phase exclusive scan of deg -> rowptr (+cursor copy) ----

// Phase A: per-block sums. 256 thr x 4 elems.
__global__ __launch_bounds__(256) void partial_kernel(const int* __restrict__ deg,
                                                      int* __restrict__ bsum) {
    __shared__ int wsum[4];
    const int tid = threadIdx.x;
    const int base = (blockIdx.x * 256 + tid) * 4;
    int s = 0;
    #pragma unroll
    for (int j = 0; j < 4; j++) {
        int idx = base + j;
        if (idx < N_NODES) s += deg[idx];
    }
    // wave reduce
    for (int off = 32; off > 0; off >>= 1) s += __shfl_down(s, off, 64);
    if ((tid & 63) == 0) wsum[tid >> 6] = s;
    __syncthreads();
    if (tid == 0) bsum[blockIdx.x] = wsum[0] + wsum[1] + wsum[2] + wsum[3];
}

// Phase B: scan the 98 block sums in one small block; also rowptr[N]=E.
__global__ __launch_bounds__(128) void scanb_kernel(const int* __restrict__ bsum,
                                                    int* __restrict__ boff,
                                                    int* __restrict__ rowptr) {
    __shared__ int s[128];
    const int tid = threadIdx.x;
    int v = (tid < SCAN_NBLOCKS) ? bsum[tid] : 0;
    s[tid] = v;
    __syncthreads();
    for (int off = 1; off < 128; off <<= 1) {
        int u = (tid >= off) ? s[tid - off] : 0;
        __syncthreads();
        s[tid] += u;
        __syncthreads();
    }
    if (tid < SCAN_NBLOCKS) boff[tid] = s[tid] - v;   // exclusive
    if (tid == 0) rowptr[N_NODES] = N_EDGES;
}

// Phase C: intra-block exclusive scan + block offset -> rowptr, cursor.
__global__ __launch_bounds__(256) void final_kernel(const int* __restrict__ deg,
                                                    const int* __restrict__ boff,
                                                    int* __restrict__ rowptr,
                                                    int* __restrict__ cursor) {
    __shared__ int wsum[4];
    const int tid = threadIdx.x;
    const int lane = tid & 63;
    const int wave = tid >> 6;
    const int base = (blockIdx.x * 256 + tid) * 4;

    int local[4];
    int tsum = 0;
    #pragma unroll
    for (int j = 0; j < 4; j++) {
        int idx = base + j;
        local[j] = (idx < N_NODES) ? deg[idx] : 0;
        tsum += local[j];
    }
    // inclusive wave scan of tsum
    int incl = tsum;
    for (int off = 1; off < 64; off <<= 1) {
        int u = __shfl_up(incl, off, 64);
        if (lane >= off) incl += u;
    }
    if (lane == 63) wsum[wave] = incl;
    __syncthreads();
    int woff = 0;
    for (int w = 0; w < 4; w++) woff += (w < wave) ? wsum[w] : 0;

    int run = boff[blockIdx.x] + woff + (incl - tsum);
    #pragma unroll
    for (int j = 0; j < 4; j++) {
        int idx = base + j;
        if (idx < N_NODES) {
            rowptr[idx] = run;
            cursor[idx] = run;
            run += local[j];
        }
    }
}

__global__ void fill_kernel(const int* __restrict__ src, const int* __restrict__ dst,
                            int* __restrict__ cursor, int* __restrict__ csr_src) {
    int e = blockIdx.x * blockDim.x + threadIdx.x;
    if (e < N_EDGES) {
        int pos = atomicAdd(&cursor[dst[e]], 1);
        csr_src[pos] = src[e];
    }
}

// out[row][c] = sum_k feat[row][k] * W[k][c]  (+ b0[c] + b1[c] if non-null)
__global__ __launch_bounds__(512) void mm_kernel(
    const float* __restrict__ feat, const float* __restrict__ W,
    const float* __restrict__ b0, const float* __restrict__ b1,
    float* __restrict__ out)
{
    __shared__ float lw[D][D];        // 64 KB
    __shared__ float lf[8][8][D];     // 32 KB

    const int tid = threadIdx.x;
    {
        const float4* Wv = (const float4*)W;
        float4* lwv = (float4*)&lw[0][0];
        for (int i = tid; i < D * D / 4; i += 512) lwv[i] = Wv[i];
    }
    __syncthreads();

    const int wave = tid >> 6;
    const int lane = tid & 63;

    float bias0 = 0.0f, bias1 = 0.0f;
    if (b0) { bias0 += b0[lane]; bias1 += b0[lane + 64]; }
    if (b1) { bias0 += b1[lane]; bias1 += b1[lane + 64]; }

    const int gw = blockIdx.x * 8 + wave;
    const int nwaves = gridDim.x * 8;

    for (int row0 = gw * 8; row0 < N_NODES; row0 += nwaves * 8) {
        {
            const float4* fv = (const float4*)(feat + (size_t)row0 * D);
            float4* lfv = (float4*)&lf[wave][0][0];
            const int limit = min(8, N_NODES - row0) * (D / 4);
            #pragma unroll
            for (int i = 0; i < 4; i++) {
                int idx = lane + i * 64;
                lfv[idx] = (idx < limit) ? fv[idx] : float4{0.f, 0.f, 0.f, 0.f};
            }
        }

        float acc[8][2];
        #pragma unroll
        for (int r = 0; r < 8; r++) { acc[r][0] = 0.f; acc[r][1] = 0.f; }

        for (int k = 0; k < D; k += 4) {
            float4 f4[8];
            #pragma unroll
            for (int r = 0; r < 8; r++)
                f4[r] = *(const float4*)&lf[wave][r][k];
            #pragma unroll
            for (int kk = 0; kk < 4; kk++) {
                const float w0 = lw[k + kk][lane];
                const float w1 = lw[k + kk][lane + 64];
                #pragma unroll
                for (int r = 0; r < 8; r++) {
                    const float f = ((const float*)&f4[r])[kk];
                    acc[r][0] = fmaf(f, w0, acc[r][0]);
                    acc[r][1] = fmaf(f, w1, acc[r][1]);
                }
            }
        }

        const int rmax = min(8, N_NODES - row0);
        for (int r = 0; r < rmax; r++) {
            out[(size_t)(row0 + r) * D + lane]      = acc[r][0] + bias0;
            out[(size_t)(row0 + r) * D + lane + 64] = acc[r][1] + bias1;
        }
    }
}

// One wave per node: sum t[src] rows over in-edges (CSR), then
// out[n] += sum * invdeg[n].  Coalesced float2 per lane; no atomics.
__global__ void gather_kernel(const float* __restrict__ t,
                              const int* __restrict__ csr_src,
                              const int* __restrict__ rowptr,
                              const float* __restrict__ invdeg,
                              float* __restrict__ out)
{
    const int lane = threadIdx.x & 63;
    const int wid = (blockIdx.x * blockDim.x + threadIdx.x) >> 6;
    const int nw = (gridDim.x * blockDim.x) >> 6;

    for (int n = wid; n < N_NODES; n += nw) {
        const int e0 = rowptr[n];
        const int e1 = rowptr[n + 1];
        float ax = 0.f, ay = 0.f;
        for (int e = e0; e < e1; e++) {
            const int s = csr_src[e];
            const float2 v = ((const float2*)(t + (size_t)s * D))[lane];
            ax += v.x; ay += v.y;
        }
        const float sc = invdeg[n];
        float2* orow = (float2*)(out + (size_t)n * D) + lane;
        float2 o = *orow;
        o.x += ax * sc;
        o.y += ay * sc;
        *orow = o;
    }
}

extern "C" void kernel_launch(void* const* d_in, const int* in_sizes, int n_in,
                              void* d_out, int out_size, void* d_ws, size_t ws_size,
                              hipStream_t stream) {
    const float* feat    = (const float*)d_in[0];
    const int*   src     = (const int*)d_in[1];
    const int*   dst     = (const int*)d_in[2];
    const float* W_self  = (const float*)d_in[3];
    const float* b_self  = (const float*)d_in[4];
    const float* W_neigh = (const float*)d_in[5];
    const float* b_neigh = (const float*)d_in[6];
    float* out = (float*)d_out;

    // ws layout: t [N*D f32] | deg [N] | invdeg [N] | rowptr [N+1] | cursor [N]
    //            | csr_src [E] | bsum [98] | boff [98]
    float* t       = (float*)d_ws;
    int*   deg     = (int*)(t + (size_t)N_NODES * D);
    float* invdeg  = (float*)(deg + N_NODES);
    int*   rowptr  = (int*)(invdeg + N_NODES);
    int*   cursor  = rowptr + (N_NODES + 1);
    int*   csr_src = cursor + N_NODES;
    int*   bsum    = csr_src + N_EDGES;
    int*   boff    = bsum + SCAN_NBLOCKS;

    zero_deg_kernel<<<(N_NODES + 255) / 256, 256, 0, stream>>>(deg);
    deg_kernel<<<(N_EDGES + 255) / 256, 256, 0, stream>>>(dst, deg);
    invdeg_kernel<<<(N_NODES + 255) / 256, 256, 0, stream>>>(deg, invdeg);

    partial_kernel<<<SCAN_NBLOCKS, 256, 0, stream>>>(deg, bsum);
    scanb_kernel<<<1, 128, 0, stream>>>(bsum, boff, rowptr);
    final_kernel<<<SCAN_NBLOCKS, 256, 0, stream>>>(deg, boff, rowptr, cursor);

    fill_kernel<<<(N_EDGES + 255) / 256, 256, 0, stream>>>(src, dst, cursor, csr_src);

    // t = feat @ W_neigh (no bias); out = feat @ W_self + b_self + b_neigh
    mm_kernel<<<256, 512, 0, stream>>>(feat, W_neigh, nullptr, nullptr, t);
    mm_kernel<<<256, 512, 0, stream>>>(feat, W_self, b_self, b_neigh, out);

    gather_kernel<<<25000, 256, 0, stream>>>(t, csr_src, rowptr, invdeg, out);
}

// Round 4
// 162.656 us; speedup vs baseline: 4.3152x; 1.8074x over previous
//
#include <hip/hip_runtime.h>

// GraphSAGE mean aggregator on MI355X.
// out = feat@W_self + b_self + b_neigh + segment_mean(t[src], dst),  t = feat@W_neigh
// R2: CSR + gather-side reduction (no float atomics).
// R3: 3-phase parallel scan.
// R4: fused bf16-MFMA double-matmul (one feat pass, both W in LDS as packed
//     fragments); t stored bf16 (halves gather fetch); gather edge-loop unroll-4.

constexpr int N_NODES = 100000;
constexpr int N_EDGES = 640000;
constexpr int D = 128;

constexpr int SCAN_ELEMS_PER_BLOCK = 1024;
constexpr int SCAN_NBLOCKS = (N_NODES + SCAN_ELEMS_PER_BLOCK - 1) / SCAN_ELEMS_PER_BLOCK; // 98

typedef __attribute__((ext_vector_type(8))) short bf16x8;
typedef __attribute__((ext_vector_type(4))) float f32x4;

__device__ __forceinline__ unsigned short f2bf(float f) {
    unsigned int u = __float_as_uint(f);
    unsigned int r = u + 0x7FFFu + ((u >> 16) & 1u);   // round-to-nearest-even
    return (unsigned short)(r >> 16);
}

// ---------------- prepass ----------------

__global__ void zero_deg_kernel(int* __restrict__ deg) {
    int i = blockIdx.x * blockDim.x + threadIdx.x;
    if (i < N_NODES) deg[i] = 0;
}

__global__ void deg_kernel(const int* __restrict__ dst, int* __restrict__ deg) {
    int e = blockIdx.x * blockDim.x + threadIdx.x;
    if (e < N_EDGES) atomicAdd(&deg[dst[e]], 1);
}

__global__ void invdeg_kernel(const int* __restrict__ deg, float* __restrict__ invdeg) {
    int i = blockIdx.x * blockDim.x + threadIdx.x;
    if (i < N_NODES) invdeg[i] = 1.0f / (float)max(deg[i], 1);
}

__global__ __launch_bounds__(256) void partial_kernel(const int* __restrict__ deg,
                                                      int* __restrict__ bsum) {
    __shared__ int wsum[4];
    const int tid = threadIdx.x;
    const int base = (blockIdx.x * 256 + tid) * 4;
    int s = 0;
    #pragma unroll
    for (int j = 0; j < 4; j++) {
        int idx = base + j;
        if (idx < N_NODES) s += deg[idx];
    }
    for (int off = 32; off > 0; off >>= 1) s += __shfl_down(s, off, 64);
    if ((tid & 63) == 0) wsum[tid >> 6] = s;
    __syncthreads();
    if (tid == 0) bsum[blockIdx.x] = wsum[0] + wsum[1] + wsum[2] + wsum[3];
}

__global__ __launch_bounds__(128) void scanb_kernel(const int* __restrict__ bsum,
                                                    int* __restrict__ boff,
                                                    int* __restrict__ rowptr) {
    __shared__ int s[128];
    const int tid = threadIdx.x;
    int v = (tid < SCAN_NBLOCKS) ? bsum[tid] : 0;
    s[tid] = v;
    __syncthreads();
    for (int off = 1; off < 128; off <<= 1) {
        int u = (tid >= off) ? s[tid - off] : 0;
        __syncthreads();
        s[tid] += u;
        __syncthreads();
    }
    if (tid < SCAN_NBLOCKS) boff[tid] = s[tid] - v;
    if (tid == 0) rowptr[N_NODES] = N_EDGES;
}

__global__ __launch_bounds__(256) void final_kernel(const int* __restrict__ deg,
                                                    const int* __restrict__ boff,
                                                    int* __restrict__ rowptr,
                                                    int* __restrict__ cursor) {
    __shared__ int wsum[4];
    const int tid = threadIdx.x;
    const int lane = tid & 63;
    const int wave = tid >> 6;
    const int base = (blockIdx.x * 256 + tid) * 4;

    int local[4];
    int tsum = 0;
    #pragma unroll
    for (int j = 0; j < 4; j++) {
        int idx = base + j;
        local[j] = (idx < N_NODES) ? deg[idx] : 0;
        tsum += local[j];
    }
    int incl = tsum;
    for (int off = 1; off < 64; off <<= 1) {
        int u = __shfl_up(incl, off, 64);
        if (lane >= off) incl += u;
    }
    if (lane == 63) wsum[wave] = incl;
    __syncthreads();
    int woff = 0;
    for (int w = 0; w < 4; w++) woff += (w < wave) ? wsum[w] : 0;

    int run = boff[blockIdx.x] + woff + (incl - tsum);
    #pragma unroll
    for (int j = 0; j < 4; j++) {
        int idx = base + j;
        if (idx < N_NODES) {
            rowptr[idx] = run;
            cursor[idx] = run;
            run += local[j];
        }
    }
}

__global__ void fill_kernel(const int* __restrict__ src, const int* __restrict__ dst,
                            int* __restrict__ cursor, int* __restrict__ csr_src) {
    int e = blockIdx.x * blockDim.x + threadIdx.x;
    if (e < N_EDGES) {
        int pos = atomicAdd(&cursor[dst[e]], 1);
        csr_src[pos] = src[e];
    }
}

// ---------------- bf16 conversion / weight packing ----------------

__global__ void fcvt_kernel(const float* __restrict__ feat, unsigned short* __restrict__ fb) {
    int i = blockIdx.x * blockDim.x + threadIdx.x;   // one float4 per thread
    if (i < N_NODES * D / 4) {
        float4 v = ((const float4*)feat)[i];
        ushort4 o;
        o.x = f2bf(v.x); o.y = f2bf(v.y); o.z = f2bf(v.z); o.w = f2bf(v.w);
        ((ushort4*)fb)[i] = o;
    }
}

// wp flat index i = (((m*4+ks)*4+h)*128 + c)*8 + r  holds  bf16(W_m[ks*32+h*8+r][c])
// Same (h,r)->k map as the A-fragment load in mmfused (k-permutation must match on
// both MFMA operands; result is invariant to the shared permutation).
__global__ void wprep_kernel(const float* __restrict__ Ws, const float* __restrict__ Wn,
                             unsigned short* __restrict__ wp) {
    int i = blockIdx.x * 256 + threadIdx.x;
    if (i >= 2 * D * D) return;
    int r  = i & 7;
    int c  = (i >> 3) & 127;
    int h  = (i >> 10) & 3;
    int ks = (i >> 12) & 3;
    int m  = i >> 14;
    const float* W = m ? Wn : Ws;
    int k = ks * 32 + h * 8 + r;
    wp[i] = f2bf(W[k * D + c]);
}

// ---------------- fused double matmul (bf16 MFMA) ----------------
// Block = 256 thr = 4 waves; each wave owns 4 row-tiles of 16 -> block = 256 rows.
// m=0: out = feat@W_self + (b_self+b_neigh)   (f32)
// m=1: t   = feat@W_neigh                     (bf16)
__global__ __launch_bounds__(256) void mmfused_kernel(
    const unsigned short* __restrict__ fb, const unsigned short* __restrict__ wp,
    const float* __restrict__ b_self, const float* __restrict__ b_neigh,
    float* __restrict__ out, unsigned short* __restrict__ t)
{
    __shared__ unsigned short lw[2 * 4 * 4 * 128 * 8];   // 64 KB packed fragments

    const int tid = threadIdx.x;
    {   // stage packed weights linearly
        const uint4* s = (const uint4*)wp;
        uint4* d = (uint4*)lw;
        #pragma unroll
        for (int i = 0; i < 16; i++) d[tid + i * 256] = s[tid + i * 256];
    }
    __syncthreads();

    const int wave = tid >> 6, lane = tid & 63;
    const int h = lane >> 4, c = lane & 15;
    const int row_base = blockIdx.x * 256 + wave * 64;

    // A fragments: a[ti][ks] = fb[row_base+ti*16+c][ks*32+h*8 .. +8)
    bf16x8 a[4][4];
    #pragma unroll
    for (int ti = 0; ti < 4; ti++) {
        int row = row_base + ti * 16 + c;
        int rowc = min(row, N_NODES - 1);             // clamp; stores are guarded
        const bf16x8* fr = (const bf16x8*)(fb + (size_t)rowc * D);
        #pragma unroll
        for (int ks = 0; ks < 4; ks++)
            a[ti][ks] = fr[ks * 4 + h];
    }

    for (int m = 0; m < 2; m++) {
        for (int ct = 0; ct < 8; ct++) {
            bf16x8 b[4];
            #pragma unroll
            for (int ks = 0; ks < 4; ks++)
                b[ks] = ((const bf16x8*)lw)[((m * 4 + ks) * 4 + h) * 128 + ct * 16 + c];

            f32x4 acc[4];
            #pragma unroll
            for (int ti = 0; ti < 4; ti++) acc[ti] = f32x4{0.f, 0.f, 0.f, 0.f};
            #pragma unroll
            for (int ks = 0; ks < 4; ks++)
                #pragma unroll
                for (int ti = 0; ti < 4; ti++)
                    acc[ti] = __builtin_amdgcn_mfma_f32_16x16x32_bf16(a[ti][ks], b[ks], acc[ti], 0, 0, 0);

            const int col = ct * 16 + c;
            if (m == 0) {
                const float bias = b_self[col] + b_neigh[col];
                #pragma unroll
                for (int ti = 0; ti < 4; ti++) {
                    if (row_base + ti * 16 < N_NODES) {
                        #pragma unroll
                        for (int q = 0; q < 4; q++) {
                            int row = row_base + ti * 16 + h * 4 + q;   // C/D: row=(lane>>4)*4+reg
                            out[(size_t)row * D + col] = acc[ti][q] + bias;
                        }
                    }
                }
            } else {
                #pragma unroll
                for (int ti = 0; ti < 4; ti++) {
                    if (row_base + ti * 16 < N_NODES) {
                        #pragma unroll
                        for (int q = 0; q < 4; q++) {
                            int row = row_base + ti * 16 + h * 4 + q;
                            t[(size_t)row * D + col] = f2bf(acc[ti][q]);
                        }
                    }
                }
            }
        }
    }
}

// ---------------- gather (bf16 t, unroll-4 ILP) ----------------
__global__ __launch_bounds__(256) void gather_kernel(
    const unsigned short* __restrict__ t, const int* __restrict__ csr_src,
    const int* __restrict__ rowptr, const float* __restrict__ invdeg,
    float* __restrict__ out)
{
    const int lane = threadIdx.x & 63;
    const int wid = (blockIdx.x * blockDim.x + threadIdx.x) >> 6;
    const int nw = (gridDim.x * blockDim.x) >> 6;

    for (int n = wid; n < N_NODES; n += nw) {
        const int e0 = rowptr[n];
        const int e1 = rowptr[n + 1];
        float ax = 0.f, ay = 0.f;
        int e = e0;
        for (; e + 4 <= e1; e += 4) {
            const int s0 = csr_src[e], s1 = csr_src[e + 1];
            const int s2 = csr_src[e + 2], s3 = csr_src[e + 3];
            const unsigned int v0 = ((const unsigned int*)(t + (size_t)s0 * D))[lane];
            const unsigned int v1 = ((const unsigned int*)(t + (size_t)s1 * D))[lane];
            const unsigned int v2 = ((const unsigned int*)(t + (size_t)s2 * D))[lane];
            const unsigned int v3 = ((const unsigned int*)(t + (size_t)s3 * D))[lane];
            ax += __uint_as_float(v0 << 16) + __uint_as_float(v1 << 16)
                + __uint_as_float(v2 << 16) + __uint_as_float(v3 << 16);
            ay += __uint_as_float(v0 & 0xFFFF0000u) + __uint_as_float(v1 & 0xFFFF0000u)
                + __uint_as_float(v2 & 0xFFFF0000u) + __uint_as_float(v3 & 0xFFFF0000u);
        }
        for (; e < e1; e++) {
            const int s = csr_src[e];
            const unsigned int v = ((const unsigned int*)(t + (size_t)s * D))[lane];
            ax += __uint_as_float(v << 16);
            ay += __uint_as_float(v & 0xFFFF0000u);
        }
        const float sc = invdeg[n];
        float2* orow = (float2*)(out + (size_t)n * D) + lane;
        float2 o = *orow;
        o.x += ax * sc;
        o.y += ay * sc;
        *orow = o;
    }
}

extern "C" void kernel_launch(void* const* d_in, const int* in_sizes, int n_in,
                              void* d_out, int out_size, void* d_ws, size_t ws_size,
                              hipStream_t stream) {
    const float* feat    = (const float*)d_in[0];
    const int*   src     = (const int*)d_in[1];
    const int*   dst     = (const int*)d_in[2];
    const float* W_self  = (const float*)d_in[3];
    const float* b_self  = (const float*)d_in[4];
    const float* W_neigh = (const float*)d_in[5];
    const float* b_neigh = (const float*)d_in[6];
    float* out = (float*)d_out;

    // ws layout: fb [N*D bf16] | t [N*D bf16] | wp [2*D*D bf16] | deg [N] |
    //            invdeg [N] | rowptr [N+1] | cursor [N] | csr_src [E] | bsum | boff
    unsigned short* fb = (unsigned short*)d_ws;
    unsigned short* t  = fb + (size_t)N_NODES * D;
    unsigned short* wp = t + (size_t)N_NODES * D;
    int*   deg     = (int*)(wp + 2 * D * D);
    float* invdeg  = (float*)(deg + N_NODES);
    int*   rowptr  = (int*)(invdeg + N_NODES);
    int*   cursor  = rowptr + (N_NODES + 1);
    int*   csr_src = cursor + N_NODES;
    int*   bsum    = csr_src + N_EDGES;
    int*   boff    = bsum + SCAN_NBLOCKS;

    zero_deg_kernel<<<(N_NODES + 255) / 256, 256, 0, stream>>>(deg);
    deg_kernel<<<(N_EDGES + 255) / 256, 256, 0, stream>>>(dst, deg);
    invdeg_kernel<<<(N_NODES + 255) / 256, 256, 0, stream>>>(deg, invdeg);

    partial_kernel<<<SCAN_NBLOCKS, 256, 0, stream>>>(deg, bsum);
    scanb_kernel<<<1, 128, 0, stream>>>(bsum, boff, rowptr);
    final_kernel<<<SCAN_NBLOCKS, 256, 0, stream>>>(deg, boff, rowptr, cursor);

    fill_kernel<<<(N_EDGES + 255) / 256, 256, 0, stream>>>(src, dst, cursor, csr_src);

    fcvt_kernel<<<(N_NODES * D / 4 + 255) / 256, 256, 0, stream>>>(feat, fb);
    wprep_kernel<<<(2 * D * D + 255) / 256, 256, 0, stream>>>(W_self, W_neigh, wp);

    mmfused_kernel<<<(N_NODES + 255) / 256, 256, 0, stream>>>(fb, wp, b_self, b_neigh, out, t);

    gather_kernel<<<25000, 256, 0, stream>>>(t, csr_src, rowptr, invdeg, out);
}

// Round 6
// 152.607 us; speedup vs baseline: 4.5993x; 1.0658x over previous
//
#include <hip/hip_runtime.h>

// GraphSAGE mean aggregator on MI355X.
// out = feat@W_self + b_self + b_neigh + segment_mean(t[src], dst),  t = feat@W_neigh
// R2: CSR + gather-side reduction (no float atomics).
// R3: 3-phase parallel scan.
// R4: fused bf16-MFMA double-matmul; t stored bf16; gather unroll-4.
// R5: fcvt folded into mmfused (in-register f32->bf16), invdeg derived from
//     rowptr in gather, memsetAsync for deg, nt hints on out RMW in gather.
// R6: fix compile — nontemporal builtins need clang ext-vector, not HIP float2.

constexpr int N_NODES = 100000;
constexpr int N_EDGES = 640000;
constexpr int D = 128;

constexpr int SCAN_ELEMS_PER_BLOCK = 1024;
constexpr int SCAN_NBLOCKS = (N_NODES + SCAN_ELEMS_PER_BLOCK - 1) / SCAN_ELEMS_PER_BLOCK; // 98

typedef __attribute__((ext_vector_type(8))) short bf16x8;
typedef __attribute__((ext_vector_type(4))) float f32x4;
typedef __attribute__((ext_vector_type(2))) float f32x2;

__device__ __forceinline__ unsigned short f2bf(float f) {
    unsigned int u = __float_as_uint(f);
    unsigned int r = u + 0x7FFFu + ((u >> 16) & 1u);   // round-to-nearest-even
    return (unsigned short)(r >> 16);
}

// ---------------- prepass ----------------

__global__ void deg_kernel(const int* __restrict__ dst, int* __restrict__ deg) {
    int e = blockIdx.x * blockDim.x + threadIdx.x;
    if (e < N_EDGES) atomicAdd(&deg[dst[e]], 1);
}

__global__ __launch_bounds__(256) void partial_kernel(const int* __restrict__ deg,
                                                      int* __restrict__ bsum) {
    __shared__ int wsum[4];
    const int tid = threadIdx.x;
    const int base = (blockIdx.x * 256 + tid) * 4;
    int s = 0;
    #pragma unroll
    for (int j = 0; j < 4; j++) {
        int idx = base + j;
        if (idx < N_NODES) s += deg[idx];
    }
    for (int off = 32; off > 0; off >>= 1) s += __shfl_down(s, off, 64);
    if ((tid & 63) == 0) wsum[tid >> 6] = s;
    __syncthreads();
    if (tid == 0) bsum[blockIdx.x] = wsum[0] + wsum[1] + wsum[2] + wsum[3];
}

__global__ __launch_bounds__(128) void scanb_kernel(const int* __restrict__ bsum,
                                                    int* __restrict__ boff,
                                                    int* __restrict__ rowptr) {
    __shared__ int s[128];
    const int tid = threadIdx.x;
    int v = (tid < SCAN_NBLOCKS) ? bsum[tid] : 0;
    s[tid] = v;
    __syncthreads();
    for (int off = 1; off < 128; off <<= 1) {
        int u = (tid >= off) ? s[tid - off] : 0;
        __syncthreads();
        s[tid] += u;
        __syncthreads();
    }
    if (tid < SCAN_NBLOCKS) boff[tid] = s[tid] - v;
    if (tid == 0) rowptr[N_NODES] = N_EDGES;
}

__global__ __launch_bounds__(256) void final_kernel(const int* __restrict__ deg,
                                                    const int* __restrict__ boff,
                                                    int* __restrict__ rowptr,
                                                    int* __restrict__ cursor) {
    __shared__ int wsum[4];
    const int tid = threadIdx.x;
    const int lane = tid & 63;
    const int wave = tid >> 6;
    const int base = (blockIdx.x * 256 + tid) * 4;

    int local[4];
    int tsum = 0;
    #pragma unroll
    for (int j = 0; j < 4; j++) {
        int idx = base + j;
        local[j] = (idx < N_NODES) ? deg[idx] : 0;
        tsum += local[j];
    }
    int incl = tsum;
    for (int off = 1; off < 64; off <<= 1) {
        int u = __shfl_up(incl, off, 64);
        if (lane >= off) incl += u;
    }
    if (lane == 63) wsum[wave] = incl;
    __syncthreads();
    int woff = 0;
    for (int w = 0; w < 4; w++) woff += (w < wave) ? wsum[w] : 0;

    int run = boff[blockIdx.x] + woff + (incl - tsum);
    #pragma unroll
    for (int j = 0; j < 4; j++) {
        int idx = base + j;
        if (idx < N_NODES) {
            rowptr[idx] = run;
            cursor[idx] = run;
            run += local[j];
        }
    }
}

__global__ void fill_kernel(const int* __restrict__ src, const int* __restrict__ dst,
                            int* __restrict__ cursor, int* __restrict__ csr_src) {
    int e = blockIdx.x * blockDim.x + threadIdx.x;
    if (e < N_EDGES) {
        int pos = atomicAdd(&cursor[dst[e]], 1);
        csr_src[pos] = src[e];
    }
}

// ---------------- weight packing ----------------
// wp flat index i = (((m*4+ks)*4+h)*128 + c)*8 + r  holds  bf16(W_m[ks*32+h*8+r][c])
// Same (h,r)->k map as the A-fragment build in mmfused (shared k-permutation).
__global__ void wprep_kernel(const float* __restrict__ Ws, const float* __restrict__ Wn,
                             unsigned short* __restrict__ wp) {
    int i = blockIdx.x * 256 + threadIdx.x;
    if (i >= 2 * D * D) return;
    int r  = i & 7;
    int c  = (i >> 3) & 127;
    int h  = (i >> 10) & 3;
    int ks = (i >> 12) & 3;
    int m  = i >> 14;
    const float* W = m ? Wn : Ws;
    int k = ks * 32 + h * 8 + r;
    wp[i] = f2bf(W[k * D + c]);
}

// ---------------- fused double matmul (bf16 MFMA, f32 feat in) ----------------
// Block = 256 thr = 4 waves; each wave owns 4 row-tiles of 16 -> block = 256 rows.
// m=0: out = feat@W_self + (b_self+b_neigh)   (f32)
// m=1: t   = feat@W_neigh                     (bf16)
__global__ __launch_bounds__(256) void mmfused_kernel(
    const float* __restrict__ feat, const unsigned short* __restrict__ wp,
    const float* __restrict__ b_self, const float* __restrict__ b_neigh,
    float* __restrict__ out, unsigned short* __restrict__ t)
{
    __shared__ unsigned short lw[2 * 4 * 4 * 128 * 8];   // 64 KB packed fragments

    const int tid = threadIdx.x;
    {   // stage packed weights linearly
        const uint4* s = (const uint4*)wp;
        uint4* d = (uint4*)lw;
        #pragma unroll
        for (int i = 0; i < 16; i++) d[tid + i * 256] = s[tid + i * 256];
    }
    __syncthreads();

    const int wave = tid >> 6, lane = tid & 63;
    const int h = lane >> 4, c = lane & 15;
    const int row_base = blockIdx.x * 256 + wave * 64;

    // A fragments from f32 feat, converted in-register:
    // a[ti][ks] = bf16(feat[row_base+ti*16+c][ks*32+h*8 .. +8))
    bf16x8 a[4][4];
    #pragma unroll
    for (int ti = 0; ti < 4; ti++) {
        int row = row_base + ti * 16 + c;
        int rowc = min(row, N_NODES - 1);             // clamp; stores are guarded
        const float4* fr = (const float4*)(feat + (size_t)rowc * D);
        #pragma unroll
        for (int ks = 0; ks < 4; ks++) {
            float4 u = fr[ks * 8 + h * 2];
            float4 v = fr[ks * 8 + h * 2 + 1];
            bf16x8 f;
            f[0] = (short)f2bf(u.x); f[1] = (short)f2bf(u.y);
            f[2] = (short)f2bf(u.z); f[3] = (short)f2bf(u.w);
            f[4] = (short)f2bf(v.x); f[5] = (short)f2bf(v.y);
            f[6] = (short)f2bf(v.z); f[7] = (short)f2bf(v.w);
            a[ti][ks] = f;
        }
    }

    #pragma unroll
    for (int m = 0; m < 2; m++) {
        for (int ct = 0; ct < 8; ct++) {
            bf16x8 b[4];
            #pragma unroll
            for (int ks = 0; ks < 4; ks++)
                b[ks] = ((const bf16x8*)lw)[((m * 4 + ks) * 4 + h) * 128 + ct * 16 + c];

            f32x4 acc[4];
            #pragma unroll
            for (int ti = 0; ti < 4; ti++) acc[ti] = f32x4{0.f, 0.f, 0.f, 0.f};
            #pragma unroll
            for (int ks = 0; ks < 4; ks++)
                #pragma unroll
                for (int ti = 0; ti < 4; ti++)
                    acc[ti] = __builtin_amdgcn_mfma_f32_16x16x32_bf16(a[ti][ks], b[ks], acc[ti], 0, 0, 0);

            const int col = ct * 16 + c;
            if (m == 0) {
                const float bias = b_self[col] + b_neigh[col];
                #pragma unroll
                for (int ti = 0; ti < 4; ti++) {
                    if (row_base + ti * 16 < N_NODES) {   // N%16==0: tile guard exact
                        #pragma unroll
                        for (int q = 0; q < 4; q++) {
                            int row = row_base + ti * 16 + h * 4 + q;   // C/D: row=(lane>>4)*4+reg
                            out[(size_t)row * D + col] = acc[ti][q] + bias;
                        }
                    }
                }
            } else {
                #pragma unroll
                for (int ti = 0; ti < 4; ti++) {
                    if (row_base + ti * 16 < N_NODES) {
                        #pragma unroll
                        for (int q = 0; q < 4; q++) {
                            int row = row_base + ti * 16 + h * 4 + q;
                            t[(size_t)row * D + col] = f2bf(acc[ti][q]);
                        }
                    }
                }
            }
        }
    }
}

// ---------------- gather (bf16 t, unroll-4, nt on out RMW) ----------------
__global__ __launch_bounds__(256) void gather_kernel(
    const unsigned short* __restrict__ t, const int* __restrict__ csr_src,
    const int* __restrict__ rowptr, float* __restrict__ out)
{
    const int lane = threadIdx.x & 63;
    const int wid = (blockIdx.x * blockDim.x + threadIdx.x) >> 6;
    const int nw = (gridDim.x * blockDim.x) >> 6;

    for (int n = wid; n < N_NODES; n += nw) {
        const int e0 = rowptr[n];
        const int e1 = rowptr[n + 1];
        float ax = 0.f, ay = 0.f;
        int e = e0;
        for (; e + 4 <= e1; e += 4) {
            const int s0 = csr_src[e], s1 = csr_src[e + 1];
            const int s2 = csr_src[e + 2], s3 = csr_src[e + 3];
            const unsigned int v0 = ((const unsigned int*)(t + (size_t)s0 * D))[lane];
            const unsigned int v1 = ((const unsigned int*)(t + (size_t)s1 * D))[lane];
            const unsigned int v2 = ((const unsigned int*)(t + (size_t)s2 * D))[lane];
            const unsigned int v3 = ((const unsigned int*)(t + (size_t)s3 * D))[lane];
            ax += __uint_as_float(v0 << 16) + __uint_as_float(v1 << 16)
                + __uint_as_float(v2 << 16) + __uint_as_float(v3 << 16);
            ay += __uint_as_float(v0 & 0xFFFF0000u) + __uint_as_float(v1 & 0xFFFF0000u)
                + __uint_as_float(v2 & 0xFFFF0000u) + __uint_as_float(v3 & 0xFFFF0000u);
        }
        for (; e < e1; e++) {
            const int s = csr_src[e];
            const unsigned int v = ((const unsigned int*)(t + (size_t)s * D))[lane];
            ax += __uint_as_float(v << 16);
            ay += __uint_as_float(v & 0xFFFF0000u);
        }
        const float sc = 1.0f / (float)max(e1 - e0, 1);
        f32x2* orow = (f32x2*)(out + (size_t)n * D) + lane;
        f32x2 o = __builtin_nontemporal_load(orow);
        o.x += ax * sc;
        o.y += ay * sc;
        __builtin_nontemporal_store(o, orow);
    }
}

extern "C" void kernel_launch(void* const* d_in, const int* in_sizes, int n_in,
                              void* d_out, int out_size, void* d_ws, size_t ws_size,
                              hipStream_t stream) {
    const float* feat    = (const float*)d_in[0];
    const int*   src     = (const int*)d_in[1];
    const int*   dst     = (const int*)d_in[2];
    const float* W_self  = (const float*)d_in[3];
    const float* b_self  = (const float*)d_in[4];
    const float* W_neigh = (const float*)d_in[5];
    const float* b_neigh = (const float*)d_in[6];
    float* out = (float*)d_out;

    // ws layout: t [N*D bf16] | wp [2*D*D bf16] | deg [N] | rowptr [N+1] |
    //            cursor [N] | csr_src [E] | bsum | boff
    unsigned short* t  = (unsigned short*)d_ws;
    unsigned short* wp = t + (size_t)N_NODES * D;
    int*   deg     = (int*)(wp + 2 * D * D);
    int*   rowptr  = deg + N_NODES;
    int*   cursor  = rowptr + (N_NODES + 1);
    int*   csr_src = cursor + N_NODES;
    int*   bsum    = csr_src + N_EDGES;
    int*   boff    = bsum + SCAN_NBLOCKS;

    (void)hipMemsetAsync(deg, 0, N_NODES * sizeof(int), stream);
    deg_kernel<<<(N_EDGES + 255) / 256, 256, 0, stream>>>(dst, deg);

    partial_kernel<<<SCAN_NBLOCKS, 256, 0, stream>>>(deg, bsum);
    scanb_kernel<<<1, 128, 0, stream>>>(bsum, boff, rowptr);
    final_kernel<<<SCAN_NBLOCKS, 256, 0, stream>>>(deg, boff, rowptr, cursor);

    fill_kernel<<<(N_EDGES + 255) / 256, 256, 0, stream>>>(src, dst, cursor, csr_src);

    wprep_kernel<<<(2 * D * D + 255) / 256, 256, 0, stream>>>(W_self, W_neigh, wp);

    mmfused_kernel<<<(N_NODES + 255) / 256, 256, 0, stream>>>(feat, wp, b_self, b_neigh, out, t);

    gather_kernel<<<25000, 256, 0, stream>>>(t, csr_src, rowptr, out);
}